// Round 7
// baseline (429.596 us; speedup 1.0000x reference)
//
#include <hip/hip_runtime.h>
#include <cstdint>
#include <cstddef>

#define D 64
#define D_FEAT 128
#define SLOPE 0.01f
#define BSH 7                 // bucket = dst >> 7  (128 nodes per bucket)
#define BW 128
#define CAP 2560              // per-bucket slot capacity (mean 2046, +11 sigma)

typedef __attribute__((ext_vector_type(8))) short bf16x8;
typedef __attribute__((ext_vector_type(4))) float f32x4;

__device__ __forceinline__ float leaky(float v) { return v >= 0.f ? v : SLOPE * v; }

__device__ __forceinline__ unsigned short f2bf(float f) {
    union { float f; unsigned u; } v; v.f = f;
    unsigned r = v.u + 0x7FFF + ((v.u >> 16) & 1);   // RNE
    return (unsigned short)(r >> 16);
}
__device__ __forceinline__ float bf2f(unsigned short b) {
    union { unsigned u; float f; } v; v.u = ((unsigned)b) << 16;
    return v.f;
}

// B-fragment of row-major fp32 W[K][64] for 16x16x32 MFMA
__device__ __forceinline__ bf16x8 wfrag(const float* W, int ks, int nt, int lane) {
    int col = nt * 16 + (lane & 15);
    int k0 = ks * 32 + ((lane >> 4) << 3);
    bf16x8 r;
#pragma unroll
    for (int j = 0; j < 8; ++j)
        r[j] = (short)f2bf(W[(k0 + j) * 64 + col]);
    return r;
}

// ---------------- init strided bucket cursors ----------------
__global__ __launch_bounds__(1024) void k_init(int* __restrict__ gcur, int nbk)
{
    int i = threadIdx.x;
    if (i < nbk) gcur[i] = i * CAP;
}

// ---------------- partition edges into strided buckets, packed (dloc<<25|src) --
__global__ __launch_bounds__(256) void k_part(const int* __restrict__ esrc,
    const int* __restrict__ edst, int* __restrict__ gcur,
    unsigned* __restrict__ pairs, int E)
{
    __shared__ int lcnt[1024];
    __shared__ int lbase[1024];
    int base = blockIdx.x * 4096;
    for (int i = threadIdx.x; i < 1024; i += 256) lcnt[i] = 0;
    __syncthreads();
    int dv[16];
#pragma unroll
    for (int i = 0; i < 16; ++i) {
        int e = base + i * 256 + threadIdx.x;
        if (e < E) {
            dv[i] = edst[e];
            atomicAdd(&lcnt[dv[i] >> BSH], 1);
        } else dv[i] = -1;
    }
    __syncthreads();
    for (int i = threadIdx.x; i < 1024; i += 256) {
        int c = lcnt[i];
        lbase[i] = c ? atomicAdd(&gcur[i], c) : 0;
    }
    __syncthreads();
    for (int i = threadIdx.x; i < 1024; i += 256) lcnt[i] = 0;
    __syncthreads();
#pragma unroll
    for (int i = 0; i < 16; ++i) {
        if (dv[i] >= 0) {
            int e = base + i * 256 + threadIdx.x;
            int b = dv[i] >> BSH;
            int r = atomicAdd(&lcnt[b], 1);
            unsigned pk = ((unsigned)(dv[i] & (BW - 1)) << 25) | (unsigned)esrc[e];
            pairs[lbase[b] + r] = pk;
        }
    }
}

// ---------------- per-bucket counting sort -> per-node ranges (coalesced) ------
__global__ __launch_bounds__(256) void k_sort(const unsigned* __restrict__ pairs,
    const int* __restrict__ gcur, int* __restrict__ nstart, int* __restrict__ nend,
    int* __restrict__ srcs, int N)
{
    __shared__ int lh[BW];
    __shared__ int cur[BW];
    __shared__ unsigned buf[CAP];
    int b = blockIdx.x;
    int node0 = b << BSH;
    int s0 = b * CAP;
    int cnt = gcur[b] - s0;
    if (threadIdx.x < BW) lh[threadIdx.x] = 0;
    __syncthreads();
    for (int i = threadIdx.x; i < cnt; i += 256)
        atomicAdd(&lh[pairs[s0 + i] >> 25], 1);
    __syncthreads();
    if (threadIdx.x < 64) {   // wave 0: exclusive scan of 128 counts, 2/lane
        int a = lh[2 * threadIdx.x], c = lh[2 * threadIdx.x + 1];
        int s = a + c, inc = s;
#pragma unroll
        for (int d = 1; d < 64; d <<= 1) {
            int u = __shfl_up(inc, d);
            if ((int)threadIdx.x >= d) inc += u;
        }
        int ex = inc - s;
        cur[2 * threadIdx.x] = ex;
        cur[2 * threadIdx.x + 1] = ex + a;
    }
    __syncthreads();
    if (threadIdx.x < BW) {
        int node = node0 + threadIdx.x;
        if (node < N) {
            nstart[node] = s0 + cur[threadIdx.x];
            nend[node]   = s0 + cur[threadIdx.x] + lh[threadIdx.x];
        }
    }
    __syncthreads();
    for (int i = threadIdx.x; i < cnt; i += 256) {
        unsigned p = pairs[s0 + i];
        int r = atomicAdd(&cur[p >> 25], 1);
        buf[r] = p & 0x1FFFFFFu;
    }
    __syncthreads();
    for (int i = threadIdx.x; i < cnt; i += 256)
        srcs[s0 + i] = (int)buf[i];
}

// ---------------- MLP + L2 norm (MFMA), fp32 in -> bf16 out ----------------
__global__ __launch_bounds__(256) void k_mlp(const float* __restrict__ F,
    const float* __restrict__ Wm, const float* __restrict__ bm,
    unsigned short* __restrict__ Xb, int N)
{
    int lane = threadIdx.x & 63, w = threadIdx.x >> 6;
    int cl = lane & 15, g = lane >> 4;
    int ntiles = (N + 63) / 64;

    bf16x8 Wmf[4][4];
#pragma unroll
    for (int ks = 0; ks < 4; ++ks)
#pragma unroll
        for (int nt = 0; nt < 4; ++nt)
            Wmf[ks][nt] = wfrag(Wm, ks, nt, lane);
    float bmv[4];
#pragma unroll
    for (int nt = 0; nt < 4; ++nt) bmv[nt] = bm[nt * 16 + cl];

    for (int tb = blockIdx.x; tb < ntiles; tb += gridDim.x) {
        int node0 = tb * 64 + w * 16;
        if (node0 >= N) continue;
        f32x4 acc[4];
#pragma unroll
        for (int nt = 0; nt < 4; ++nt) acc[nt] = (f32x4){0.f, 0.f, 0.f, 0.f};
#pragma unroll
        for (int ks = 0; ks < 4; ++ks) {
            const float4* fp = (const float4*)(F + (size_t)(node0 + cl) * D_FEAT + ks * 32 + g * 8);
            float4 a = fp[0], b = fp[1];
            bf16x8 af;
            af[0] = (short)f2bf(a.x); af[1] = (short)f2bf(a.y);
            af[2] = (short)f2bf(a.z); af[3] = (short)f2bf(a.w);
            af[4] = (short)f2bf(b.x); af[5] = (short)f2bf(b.y);
            af[6] = (short)f2bf(b.z); af[7] = (short)f2bf(b.w);
#pragma unroll
            for (int nt = 0; nt < 4; ++nt)
                acc[nt] = __builtin_amdgcn_mfma_f32_16x16x32_bf16(af, Wmf[ks][nt], acc[nt], 0, 0, 0);
        }
        float ss[4] = {0.f, 0.f, 0.f, 0.f};
#pragma unroll
        for (int nt = 0; nt < 4; ++nt)
#pragma unroll
            for (int i = 0; i < 4; ++i) {
                float v = acc[nt][i] + bmv[nt];
                acc[nt][i] = v;
                ss[i] += v * v;
            }
#pragma unroll
        for (int off = 8; off >= 1; off >>= 1)
#pragma unroll
            for (int i = 0; i < 4; ++i)
                ss[i] += __shfl_xor(ss[i], off);
        float inv[4];
#pragma unroll
        for (int i = 0; i < 4; ++i)
            inv[i] = 1.f / fmaxf(sqrtf(ss[i]), 1e-12f);
#pragma unroll
        for (int nt = 0; nt < 4; ++nt)
#pragma unroll
            for (int i = 0; i < 4; ++i)
                Xb[(size_t)(node0 + g * 4 + i) * D + nt * 16 + cl] = f2bf(acc[nt][i] * inv[i]);
    }
}

// ---------------- fused gather + combine (MFMA):
// agg = CSR-gather(Xb); O = leaky( leaky(agg@Wc)@Wg + bg + leaky(X@Wl+bl) + ID )
__global__ __launch_bounds__(256) void k_fused(
    const int* __restrict__ nstart, const int* __restrict__ nend,
    const int* __restrict__ srcs, const unsigned short* __restrict__ Xb,
    const float* __restrict__ Wc,
    const float* __restrict__ Wl, const float* __restrict__ bl,
    const float* __restrict__ Wg, const float* __restrict__ bg,
    const float* __restrict__ ID,
    unsigned short* Ob, float* Of, int N)
{
    __shared__ float agg[4][16][67];          // per-wave gather buffer (2-way banks)
    __shared__ unsigned short tl[4][16][72];  // per-wave transpose buffer
    int lane = threadIdx.x & 63, w = threadIdx.x >> 6;
    int cl = lane & 15, g = lane >> 4;
    int ntiles = (N + 63) / 64;

    bf16x8 Wcf[2][4], Wlf[2][4], Wgf[2][4];
#pragma unroll
    for (int ks = 0; ks < 2; ++ks)
#pragma unroll
        for (int nt = 0; nt < 4; ++nt) {
            Wcf[ks][nt] = wfrag(Wc, ks, nt, lane);
            Wlf[ks][nt] = wfrag(Wl, ks, nt, lane);
            Wgf[ks][nt] = wfrag(Wg, ks, nt, lane);
        }
    float blv[4], bgv[4];
#pragma unroll
    for (int nt = 0; nt < 4; ++nt) {
        blv[nt] = bl[nt * 16 + cl];
        bgv[nt] = bg[nt * 16 + cl];
    }

    for (int tb = blockIdx.x; tb < ntiles; tb += gridDim.x) {
        int node0 = tb * 64 + w * 16;
        // ---- gather phase: this wave's 16 nodes (quarter-wave per edge) ----
        for (int nn = 0; nn < 16; ++nn) {
            int node = node0 + nn;
            if (node >= N) break;
            int s = nstart[node], e = nend[node];
            float4 acc = {0.f, 0.f, 0.f, 0.f};
            for (int base = s; base < e; base += 64) {
                int m = e - base; if (m > 64) m = 64;
                int sid = (base + lane < e) ? srcs[base + lane] : 0;
                int iters = (m + 3) >> 2;
                for (int j = 0; j < iters; ++j) {
                    int idx = (j << 2) | g;
                    int sv = __shfl(sid, idx);
                    if (idx < m) {
                        uint2 u = *(const uint2*)(Xb + (size_t)sv * D + cl * 4);
                        acc.x += bf2f((unsigned short)(u.x & 0xFFFFu));
                        acc.y += bf2f((unsigned short)(u.x >> 16));
                        acc.z += bf2f((unsigned short)(u.y & 0xFFFFu));
                        acc.w += bf2f((unsigned short)(u.y >> 16));
                    }
                }
            }
#pragma unroll
            for (int d = 32; d >= 16; d >>= 1) {
                acc.x += __shfl_xor(acc.x, d);
                acc.y += __shfl_xor(acc.y, d);
                acc.z += __shfl_xor(acc.z, d);
                acc.w += __shfl_xor(acc.w, d);
            }
            if (g == 0) {
                agg[w][nn][cl * 4 + 0] = acc.x;
                agg[w][nn][cl * 4 + 1] = acc.y;
                agg[w][nn][cl * 4 + 2] = acc.z;
                agg[w][nn][cl * 4 + 3] = acc.w;
            }
        }
        __syncthreads();
        bool active = node0 < N;          // N % 16 == 0 -> whole wave-tile valid
        f32x4 accL[4], accG[4];
        if (active) {
            const bf16x8* xr = (const bf16x8*)(Xb + (size_t)(node0 + cl) * D + g * 8);
            bf16x8 xf0 = xr[0], xf1 = xr[4];
            bf16x8 af0, af1;
#pragma unroll
            for (int j = 0; j < 8; ++j) {
                af0[j] = (short)f2bf(agg[w][cl][g * 8 + j]);
                af1[j] = (short)f2bf(agg[w][cl][32 + g * 8 + j]);
            }
            f32x4 accC[4];
#pragma unroll
            for (int nt = 0; nt < 4; ++nt) {
                f32x4 z = (f32x4){0.f, 0.f, 0.f, 0.f};
                accL[nt] = __builtin_amdgcn_mfma_f32_16x16x32_bf16(xf1, Wlf[1][nt],
                            __builtin_amdgcn_mfma_f32_16x16x32_bf16(xf0, Wlf[0][nt], z, 0, 0, 0), 0, 0, 0);
                accC[nt] = __builtin_amdgcn_mfma_f32_16x16x32_bf16(af1, Wcf[1][nt],
                            __builtin_amdgcn_mfma_f32_16x16x32_bf16(af0, Wcf[0][nt], z, 0, 0, 0), 0, 0, 0);
            }
#pragma unroll
            for (int nt = 0; nt < 4; ++nt)
#pragma unroll
                for (int i = 0; i < 4; ++i)
                    tl[w][g * 4 + i][nt * 16 + cl] = f2bf(leaky(accC[nt][i]));
        }
        __syncthreads();
        if (active) {
            const bf16x8* tr = (const bf16x8*)&tl[w][cl][g * 8];
            bf16x8 tf0 = tr[0], tf1 = tr[4];
#pragma unroll
            for (int nt = 0; nt < 4; ++nt) {
                f32x4 z = (f32x4){0.f, 0.f, 0.f, 0.f};
                accG[nt] = __builtin_amdgcn_mfma_f32_16x16x32_bf16(tf1, Wgf[1][nt],
                            __builtin_amdgcn_mfma_f32_16x16x32_bf16(tf0, Wgf[0][nt], z, 0, 0, 0), 0, 0, 0);
            }
#pragma unroll
            for (int nt = 0; nt < 4; ++nt) {
                int col = nt * 16 + cl;
#pragma unroll
                for (int i = 0; i < 4; ++i) {
                    size_t row = (size_t)(node0 + g * 4 + i);
                    float xh = leaky(accL[nt][i] + blv[nt]) + ID[row * D + col];
                    float o = leaky(accG[nt][i] + bgv[nt] + xh);
                    if (Ob) Ob[row * D + col] = f2bf(o);
                    else    Of[row * D + col] = o;
                }
            }
        }
        __syncthreads();
    }
}

extern "C" void kernel_launch(void* const* d_in, const int* in_sizes, int n_in,
                              void* d_out, int out_size, void* d_ws, size_t ws_size,
                              hipStream_t stream)
{
    const float* features = (const float*)d_in[0];
    const float* id_emb   = (const float*)d_in[1];
    const int*   eidx     = (const int*)d_in[2];
    const float* W_mlp    = (const float*)d_in[3];
    const float* b_mlp    = (const float*)d_in[4];
    const float* Wc1 = (const float*)d_in[5];
    const float* Wl1 = (const float*)d_in[6];
    const float* bl1 = (const float*)d_in[7];
    const float* Wg1 = (const float*)d_in[8];
    const float* bg1 = (const float*)d_in[9];
    const float* Wc2 = (const float*)d_in[10];
    const float* Wl2 = (const float*)d_in[11];
    const float* bl2 = (const float*)d_in[12];
    const float* Wg2 = (const float*)d_in[13];
    const float* bg2 = (const float*)d_in[14];

    int N = in_sizes[0] / D_FEAT;
    int E = in_sizes[2] / 2;
    const int* esrc = eidx;
    const int* edst = eidx + E;
    int nbk = (N + BW - 1) >> BSH;               // 782 for N=100000

    unsigned short* Xb = (unsigned short*)d_ws;  // [N][64] bf16 (x0)
    unsigned short* X1 = Xb + (size_t)N * D;     // [N][64] bf16 (x1)
    int* srcs   = (int*)(X1 + (size_t)N * D);    // [nbk*CAP] bucket-strided
    int* nstart = srcs + (size_t)nbk * CAP;      // [N]
    int* nend   = nstart + N;                    // [N]
    int* gcur   = nend + N;                      // [1024]

    // pairs scratch lives in d_out (25.6 MB >= nbk*CAP*4 = 8.2 MB); fully dead
    // before the final fused kernel writes d_out.
    unsigned* pairs = (unsigned*)d_out;

    dim3 blk(256);
    int ntiles = (N + 63) / 64;
    int mgrid = ntiles < 512 ? ntiles : 512;
    int egrid = (E + 4095) / 4096;

    // bucket CSR build (shared by both layers)
    k_init<<<1, 1024, 0, stream>>>(gcur, nbk);
    k_part<<<egrid, blk, 0, stream>>>(esrc, edst, gcur, pairs, E);
    k_sort<<<nbk, blk, 0, stream>>>(pairs, gcur, nstart, nend, srcs, N);

    k_mlp<<<mgrid, blk, 0, stream>>>(features, W_mlp, b_mlp, Xb, N);

    // layer 1: gather+combine fused, writes X1
    k_fused<<<ntiles, blk, 0, stream>>>(nstart, nend, srcs, Xb,
                                        Wc1, Wl1, bl1, Wg1, bg1, id_emb,
                                        X1, (float*)nullptr, N);
    // layer 2: reads X1, writes fp32 d_out
    k_fused<<<ntiles, blk, 0, stream>>>(nstart, nend, srcs, X1,
                                        Wc2, Wl2, bl2, Wg2, bg2, id_emb,
                                        (unsigned short*)nullptr, (float*)d_out, N);
}

// Round 8
// 194.375 us; speedup vs baseline: 2.2101x; 2.2101x over previous
//
#include <hip/hip_runtime.h>
#include <cstdint>
#include <cstddef>

#define D 64
#define D_FEAT 128
#define SLOPE 0.01f
#define BSH 7                 // bucket = dst >> 7  (128 nodes per bucket)
#define BW 128
#define CAP 2560              // per-bucket slot capacity (mean 2046, +11 sigma)

typedef __attribute__((ext_vector_type(8))) short bf16x8;
typedef __attribute__((ext_vector_type(4))) float f32x4;

__device__ __forceinline__ float leaky(float v) { return v >= 0.f ? v : SLOPE * v; }

__device__ __forceinline__ unsigned short f2bf(float f) {
    union { float f; unsigned u; } v; v.f = f;
    unsigned r = v.u + 0x7FFF + ((v.u >> 16) & 1);   // RNE
    return (unsigned short)(r >> 16);
}
__device__ __forceinline__ float bf2f(unsigned short b) {
    union { unsigned u; float f; } v; v.u = ((unsigned)b) << 16;
    return v.f;
}

// B-fragment of row-major fp32 W[K][64] for 16x16x32 MFMA
__device__ __forceinline__ bf16x8 wfrag(const float* W, int ks, int nt, int lane) {
    int col = nt * 16 + (lane & 15);
    int k0 = ks * 32 + ((lane >> 4) << 3);
    bf16x8 r;
#pragma unroll
    for (int j = 0; j < 8; ++j)
        r[j] = (short)f2bf(W[(k0 + j) * 64 + col]);
    return r;
}

// ---------------- init strided bucket cursors ----------------
__global__ __launch_bounds__(1024) void k_init(int* __restrict__ gcur, int nbk)
{
    int i = threadIdx.x;
    if (i < nbk) gcur[i] = i * CAP;
}

// ---------------- partition edges into strided buckets, packed (dloc<<25|src) --
__global__ __launch_bounds__(256) void k_part(const int* __restrict__ esrc,
    const int* __restrict__ edst, int* __restrict__ gcur,
    unsigned* __restrict__ pairs, int E)
{
    __shared__ int lcnt[1024];
    __shared__ int lbase[1024];
    int base = blockIdx.x * 4096;
    for (int i = threadIdx.x; i < 1024; i += 256) lcnt[i] = 0;
    __syncthreads();
    int dv[16];
#pragma unroll
    for (int i = 0; i < 16; ++i) {
        int e = base + i * 256 + threadIdx.x;
        if (e < E) {
            dv[i] = edst[e];
            atomicAdd(&lcnt[dv[i] >> BSH], 1);
        } else dv[i] = -1;
    }
    __syncthreads();
    for (int i = threadIdx.x; i < 1024; i += 256) {
        int c = lcnt[i];
        lbase[i] = c ? atomicAdd(&gcur[i], c) : 0;
    }
    __syncthreads();
    for (int i = threadIdx.x; i < 1024; i += 256) lcnt[i] = 0;
    __syncthreads();
#pragma unroll
    for (int i = 0; i < 16; ++i) {
        if (dv[i] >= 0) {
            int e = base + i * 256 + threadIdx.x;
            int b = dv[i] >> BSH;
            int r = atomicAdd(&lcnt[b], 1);
            unsigned pk = ((unsigned)(dv[i] & (BW - 1)) << 25) | (unsigned)esrc[e];
            pairs[lbase[b] + r] = pk;
        }
    }
}

// ---------------- per-bucket counting sort -> per-node ranges (coalesced) ------
__global__ __launch_bounds__(256) void k_sort(const unsigned* __restrict__ pairs,
    const int* __restrict__ gcur, int* __restrict__ nstart, int* __restrict__ nend,
    int* __restrict__ srcs, int N)
{
    __shared__ int lh[BW];
    __shared__ int cur[BW];
    __shared__ unsigned buf[CAP];
    int b = blockIdx.x;
    int node0 = b << BSH;
    int s0 = b * CAP;
    int cnt = gcur[b] - s0;
    if (threadIdx.x < BW) lh[threadIdx.x] = 0;
    __syncthreads();
    for (int i = threadIdx.x; i < cnt; i += 256)
        atomicAdd(&lh[pairs[s0 + i] >> 25], 1);
    __syncthreads();
    if (threadIdx.x < 64) {   // wave 0: exclusive scan of 128 counts, 2/lane
        int a = lh[2 * threadIdx.x], c = lh[2 * threadIdx.x + 1];
        int s = a + c, inc = s;
#pragma unroll
        for (int d = 1; d < 64; d <<= 1) {
            int u = __shfl_up(inc, d);
            if ((int)threadIdx.x >= d) inc += u;
        }
        int ex = inc - s;
        cur[2 * threadIdx.x] = ex;
        cur[2 * threadIdx.x + 1] = ex + a;
    }
    __syncthreads();
    if (threadIdx.x < BW) {
        int node = node0 + threadIdx.x;
        if (node < N) {
            nstart[node] = s0 + cur[threadIdx.x];
            nend[node]   = s0 + cur[threadIdx.x] + lh[threadIdx.x];
        }
    }
    __syncthreads();
    for (int i = threadIdx.x; i < cnt; i += 256) {
        unsigned p = pairs[s0 + i];
        int r = atomicAdd(&cur[p >> 25], 1);
        buf[r] = p & 0x1FFFFFFu;
    }
    __syncthreads();
    for (int i = threadIdx.x; i < cnt; i += 256)
        srcs[s0 + i] = (int)buf[i];
}

// ---------------- MLP + L2 norm (MFMA), fp32 in -> bf16 out ----------------
__global__ __launch_bounds__(256) void k_mlp(const float* __restrict__ F,
    const float* __restrict__ Wm, const float* __restrict__ bm,
    unsigned short* __restrict__ Xb, int N)
{
    int lane = threadIdx.x & 63, w = threadIdx.x >> 6;
    int cl = lane & 15, g = lane >> 4;
    int ntiles = (N + 63) / 64;

    bf16x8 Wmf[4][4];
#pragma unroll
    for (int ks = 0; ks < 4; ++ks)
#pragma unroll
        for (int nt = 0; nt < 4; ++nt)
            Wmf[ks][nt] = wfrag(Wm, ks, nt, lane);
    float bmv[4];
#pragma unroll
    for (int nt = 0; nt < 4; ++nt) bmv[nt] = bm[nt * 16 + cl];

    for (int tb = blockIdx.x; tb < ntiles; tb += gridDim.x) {
        int node0 = tb * 64 + w * 16;
        if (node0 >= N) continue;
        f32x4 acc[4];
#pragma unroll
        for (int nt = 0; nt < 4; ++nt) acc[nt] = (f32x4){0.f, 0.f, 0.f, 0.f};
#pragma unroll
        for (int ks = 0; ks < 4; ++ks) {
            const float4* fp = (const float4*)(F + (size_t)(node0 + cl) * D_FEAT + ks * 32 + g * 8);
            float4 a = fp[0], b = fp[1];
            bf16x8 af;
            af[0] = (short)f2bf(a.x); af[1] = (short)f2bf(a.y);
            af[2] = (short)f2bf(a.z); af[3] = (short)f2bf(a.w);
            af[4] = (short)f2bf(b.x); af[5] = (short)f2bf(b.y);
            af[6] = (short)f2bf(b.z); af[7] = (short)f2bf(b.w);
#pragma unroll
            for (int nt = 0; nt < 4; ++nt)
                acc[nt] = __builtin_amdgcn_mfma_f32_16x16x32_bf16(af, Wmf[ks][nt], acc[nt], 0, 0, 0);
        }
        float ss[4] = {0.f, 0.f, 0.f, 0.f};
#pragma unroll
        for (int nt = 0; nt < 4; ++nt)
#pragma unroll
            for (int i = 0; i < 4; ++i) {
                float v = acc[nt][i] + bmv[nt];
                acc[nt][i] = v;
                ss[i] += v * v;
            }
#pragma unroll
        for (int off = 8; off >= 1; off >>= 1)
#pragma unroll
            for (int i = 0; i < 4; ++i)
                ss[i] += __shfl_xor(ss[i], off);
        float inv[4];
#pragma unroll
        for (int i = 0; i < 4; ++i)
            inv[i] = 1.f / fmaxf(sqrtf(ss[i]), 1e-12f);
#pragma unroll
        for (int nt = 0; nt < 4; ++nt)
#pragma unroll
            for (int i = 0; i < 4; ++i)
                Xb[(size_t)(node0 + g * 4 + i) * D + nt * 16 + cl] = f2bf(acc[nt][i] * inv[i]);
    }
}

// ---------------- gather: Agg[n] = sum_{edges dst==n} Xb[src] ----------------
// eighth-wave per edge: 8 lanes x 16B (uint4) cover one 64xbf16 row; 8 edges/iter
__global__ __launch_bounds__(256) void k_gather(const int* __restrict__ nstart,
    const int* __restrict__ nend, const int* __restrict__ srcs,
    const unsigned short* __restrict__ Xb, unsigned short* __restrict__ Ab, int N)
{
    int lane = threadIdx.x & 63, w = threadIdx.x >> 6;
    int node = blockIdx.x * 4 + w;
    if (node >= N) return;
    int start = nstart[node];
    int end = nend[node];
    int g = lane >> 3;          // 8 groups of 8 lanes, one edge each
    int li = lane & 7;          // li covers cols [li*8, li*8+8)
    float acc[8] = {0.f, 0.f, 0.f, 0.f, 0.f, 0.f, 0.f, 0.f};
    for (int base = start; base < end; base += 64) {
        int m = end - base; if (m > 64) m = 64;
        int sid = (base + lane < end) ? srcs[base + lane] : 0;
        int iters = (m + 7) >> 3;
        for (int j = 0; j < iters; ++j) {
            int idx = (j << 3) | g;
            int s = __shfl(sid, idx);
            if (idx < m) {
                uint4 u = *(const uint4*)(Xb + (size_t)s * D + li * 8);
                acc[0] += bf2f((unsigned short)(u.x & 0xFFFFu));
                acc[1] += bf2f((unsigned short)(u.x >> 16));
                acc[2] += bf2f((unsigned short)(u.y & 0xFFFFu));
                acc[3] += bf2f((unsigned short)(u.y >> 16));
                acc[4] += bf2f((unsigned short)(u.z & 0xFFFFu));
                acc[5] += bf2f((unsigned short)(u.z >> 16));
                acc[6] += bf2f((unsigned short)(u.w & 0xFFFFu));
                acc[7] += bf2f((unsigned short)(u.w >> 16));
            }
        }
    }
#pragma unroll
    for (int d = 32; d >= 8; d >>= 1)
#pragma unroll
        for (int i = 0; i < 8; ++i)
            acc[i] += __shfl_xor(acc[i], d);
    if (g == 0) {
        uint4 o;
        o.x = (unsigned)f2bf(acc[0]) | ((unsigned)f2bf(acc[1]) << 16);
        o.y = (unsigned)f2bf(acc[2]) | ((unsigned)f2bf(acc[3]) << 16);
        o.z = (unsigned)f2bf(acc[4]) | ((unsigned)f2bf(acc[5]) << 16);
        o.w = (unsigned)f2bf(acc[6]) | ((unsigned)f2bf(acc[7]) << 16);
        *(uint4*)(Ab + (size_t)node * D + li * 8) = o;
    }
}

// ---------------- fused combine (MFMA):
// O = leaky( leaky(Agg@Wc)@Wg + bg + leaky(X@Wl + bl) + ID ) ----------------
__global__ __launch_bounds__(256) void k_combine(
    const unsigned short* Xb, const unsigned short* __restrict__ Ab,
    const float* __restrict__ Wc,
    const float* __restrict__ Wl, const float* __restrict__ bl,
    const float* __restrict__ Wg, const float* __restrict__ bg,
    const float* __restrict__ ID,
    unsigned short* Ob, float* Of, int N)
{
    __shared__ unsigned short tl[4][16][72];
    int lane = threadIdx.x & 63, w = threadIdx.x >> 6;
    int cl = lane & 15, g = lane >> 4;
    int ntiles = (N + 63) / 64;

    bf16x8 Wcf[2][4], Wlf[2][4], Wgf[2][4];
#pragma unroll
    for (int ks = 0; ks < 2; ++ks)
#pragma unroll
        for (int nt = 0; nt < 4; ++nt) {
            Wcf[ks][nt] = wfrag(Wc, ks, nt, lane);
            Wlf[ks][nt] = wfrag(Wl, ks, nt, lane);
            Wgf[ks][nt] = wfrag(Wg, ks, nt, lane);
        }
    float blv[4], bgv[4];
#pragma unroll
    for (int nt = 0; nt < 4; ++nt) {
        blv[nt] = bl[nt * 16 + cl];
        bgv[nt] = bg[nt * 16 + cl];
    }

    for (int tb = blockIdx.x; tb < ntiles; tb += gridDim.x) {
        int node0 = tb * 64 + w * 16;
        bool active = node0 < N;
        f32x4 accL[4], accG[4];
        if (active) {
            const bf16x8* xr = (const bf16x8*)(Xb + (size_t)(node0 + cl) * D + g * 8);
            const bf16x8* ar = (const bf16x8*)(Ab + (size_t)(node0 + cl) * D + g * 8);
            bf16x8 xf0 = xr[0], xf1 = xr[4];
            bf16x8 af0 = ar[0], af1 = ar[4];
            f32x4 accC[4];
#pragma unroll
            for (int nt = 0; nt < 4; ++nt) {
                f32x4 z = (f32x4){0.f, 0.f, 0.f, 0.f};
                accL[nt] = __builtin_amdgcn_mfma_f32_16x16x32_bf16(xf1, Wlf[1][nt],
                            __builtin_amdgcn_mfma_f32_16x16x32_bf16(xf0, Wlf[0][nt], z, 0, 0, 0), 0, 0, 0);
                accC[nt] = __builtin_amdgcn_mfma_f32_16x16x32_bf16(af1, Wcf[1][nt],
                            __builtin_amdgcn_mfma_f32_16x16x32_bf16(af0, Wcf[0][nt], z, 0, 0, 0), 0, 0, 0);
            }
#pragma unroll
            for (int nt = 0; nt < 4; ++nt)
#pragma unroll
                for (int i = 0; i < 4; ++i)
                    tl[w][g * 4 + i][nt * 16 + cl] = f2bf(leaky(accC[nt][i]));
        }
        __syncthreads();
        if (active) {
            const bf16x8* tr = (const bf16x8*)&tl[w][cl][g * 8];
            bf16x8 tf0 = tr[0], tf1 = tr[4];
#pragma unroll
            for (int nt = 0; nt < 4; ++nt) {
                f32x4 z = (f32x4){0.f, 0.f, 0.f, 0.f};
                accG[nt] = __builtin_amdgcn_mfma_f32_16x16x32_bf16(tf1, Wgf[1][nt],
                            __builtin_amdgcn_mfma_f32_16x16x32_bf16(tf0, Wgf[0][nt], z, 0, 0, 0), 0, 0, 0);
            }
#pragma unroll
            for (int nt = 0; nt < 4; ++nt) {
                int col = nt * 16 + cl;
#pragma unroll
                for (int i = 0; i < 4; ++i) {
                    size_t row = (size_t)(node0 + g * 4 + i);
                    float xh = leaky(accL[nt][i] + blv[nt]) + ID[row * D + col];
                    float o = leaky(accG[nt][i] + bgv[nt] + xh);
                    if (Ob) Ob[row * D + col] = f2bf(o);
                    else    Of[row * D + col] = o;
                }
            }
        }
        __syncthreads();
    }
}

extern "C" void kernel_launch(void* const* d_in, const int* in_sizes, int n_in,
                              void* d_out, int out_size, void* d_ws, size_t ws_size,
                              hipStream_t stream)
{
    const float* features = (const float*)d_in[0];
    const float* id_emb   = (const float*)d_in[1];
    const int*   eidx     = (const int*)d_in[2];
    const float* W_mlp    = (const float*)d_in[3];
    const float* b_mlp    = (const float*)d_in[4];
    const float* Wc1 = (const float*)d_in[5];
    const float* Wl1 = (const float*)d_in[6];
    const float* bl1 = (const float*)d_in[7];
    const float* Wg1 = (const float*)d_in[8];
    const float* bg1 = (const float*)d_in[9];
    const float* Wc2 = (const float*)d_in[10];
    const float* Wl2 = (const float*)d_in[11];
    const float* bl2 = (const float*)d_in[12];
    const float* Wg2 = (const float*)d_in[13];
    const float* bg2 = (const float*)d_in[14];

    int N = in_sizes[0] / D_FEAT;
    int E = in_sizes[2] / 2;
    const int* esrc = eidx;
    const int* edst = eidx + E;
    int nbk = (N + BW - 1) >> BSH;               // 782 for N=100000

    unsigned short* Xb = (unsigned short*)d_ws;  // [N][64] bf16
    unsigned short* Ab = Xb + (size_t)N * D;     // [N][64] bf16
    int* srcs   = (int*)(Ab + (size_t)N * D);    // [nbk*CAP] bucket-strided
    int* nstart = srcs + (size_t)nbk * CAP;      // [N]
    int* nend   = nstart + N;                    // [N]
    int* gcur   = nend + N;                      // [1024]

    // pairs scratch lives in d_out (25.6 MB >= nbk*CAP*4 = 8.0 MB); fully dead
    // before the final combine writes d_out.
    unsigned* pairs = (unsigned*)d_out;

    dim3 blk(256);
    int ntiles = (N + 63) / 64;
    int mgrid = ntiles < 512 ? ntiles : 512;
    int egrid = (E + 4095) / 4096;

    // bucket CSR build (shared by both layers)
    k_init<<<1, 1024, 0, stream>>>(gcur, nbk);
    k_part<<<egrid, blk, 0, stream>>>(esrc, edst, gcur, pairs, E);
    k_sort<<<nbk, blk, 0, stream>>>(pairs, gcur, nstart, nend, srcs, N);

    k_mlp<<<mgrid, blk, 0, stream>>>(features, W_mlp, b_mlp, Xb, N);

    // layer 1  (combine writes x1 bf16 in-place over Xb)
    k_gather <<<(N + 3) / 4, blk, 0, stream>>>(nstart, nend, srcs, Xb, Ab, N);
    k_combine<<<mgrid, blk, 0, stream>>>(Xb, Ab, Wc1, Wl1, bl1, Wg1, bg1, id_emb,
                                         Xb, (float*)nullptr, N);

    // layer 2
    k_gather <<<(N + 3) / 4, blk, 0, stream>>>(nstart, nend, srcs, Xb, Ab, N);
    k_combine<<<mgrid, blk, 0, stream>>>(Xb, Ab, Wc2, Wl2, bl2, Wg2, bg2, id_emb,
                                         (unsigned short*)nullptr, (float*)d_out, N);
}